// Round 1
// 638.478 us; speedup vs baseline: 1.0283x; 1.0283x over previous
//
#include <hip/hip_runtime.h>

typedef unsigned short ushort_t;
using short8  = __attribute__((ext_vector_type(8))) short;
using floatx4 = __attribute__((ext_vector_type(4))) float;
using intx4   = __attribute__((ext_vector_type(4))) int;
using fx4     = __attribute__((ext_vector_type(4))) float;

__device__ __forceinline__ ushort_t f2bf(float f) {
  unsigned int x = __builtin_bit_cast(unsigned int, f);
  x += 0x7fffu + ((x >> 16) & 1u);           // RNE
  return (ushort_t)(x >> 16);
}

__device__ __forceinline__ void gld16(const ushort_t* g, ushort_t* l) {
  __builtin_amdgcn_global_load_lds(
      (const __attribute__((address_space(1))) void*)(unsigned long long)(uintptr_t)g,
      (__attribute__((address_space(3))) void*)l, 16, 0, 0);
}

// vmcnt(0) drain + workgroup barrier (raw: does NOT drain prefetches issued after)
__device__ __forceinline__ void wait_bar() {
  asm volatile("s_waitcnt vmcnt(0)" ::: "memory");
  __builtin_amdgcn_s_barrier();
  __builtin_amdgcn_sched_barrier(0);
}
__device__ __forceinline__ void vwait0() {
  asm volatile("s_waitcnt vmcnt(0)" ::: "memory");
  __builtin_amdgcn_sched_barrier(0);
}
__device__ __forceinline__ void lwait0() {
  asm volatile("s_waitcnt lgkmcnt(0)" ::: "memory");
  __builtin_amdgcn_sched_barrier(0);
}

// ---------------- merged prep kernel ----------------
// blocks [0, 81920): adj cast (f32 out + bf16 slices 1,4) — nontemporal stream
// blocks [81920, 82944): X transpose -> XT bf16
// blocks [82944, 84992): weight prep
__global__ __launch_bounds__(256) void k_prep(const int* __restrict__ graph,
                                              float* __restrict__ adj_out,
                                              ushort_t* __restrict__ adjb,
                                              const float* __restrict__ gn,
                                              ushort_t* __restrict__ XT,
                                              const float* __restrict__ Wg1, const float* __restrict__ Wg2,
                                              const float* __restrict__ Wf1, const float* __restrict__ Wf2,
                                              ushort_t* __restrict__ W1T, ushort_t* __restrict__ W2pT,
                                              ushort_t* __restrict__ Wf1T, ushort_t* __restrict__ Wf2T) {
  __shared__ float t[64][68];
  const int bid = blockIdx.x;
  if (bid < 81920) {
    const size_t i = (size_t)bid * 256 + threadIdx.x;   // int4 index
    intx4 v = __builtin_nontemporal_load((const intx4*)graph + i);
    fx4 f; f[0] = (float)v[0]; f[1] = (float)v[1]; f[2] = (float)v[2]; f[3] = (float)v[3];
    __builtin_nontemporal_store(f, (fx4*)adj_out + i);
    const size_t e0 = i * 4;
    const unsigned sb = (unsigned)(e0 >> 20);
    const unsigned s = sb % 5u, b = sb / 5u;
    if (s == 1u || s == 4u) {
      const unsigned tt = (s == 4u) ? 1u : 0u;
      ushort4 h;
      h.x = f2bf(f[0]); h.y = f2bf(f[1]); h.z = f2bf(f[2]); h.w = f2bf(f[3]);
      *(ushort4*)(adjb + (((size_t)(b * 2 + tt)) << 20) + (e0 & 0xFFFFFu)) = h;
    }
  } else if (bid < 82944) {
    const int id = bid - 81920;
    const int kt = id & 15, dt = (id >> 4) & 3, b = id >> 6;
    const int r  = threadIdx.x >> 4;
    const int c4 = (threadIdx.x & 15) * 4;
#pragma unroll
    for (int rr = 0; rr < 4; rr++) {
      const int kl = rr * 16 + r;
      float4 v = *(const float4*)(gn + ((size_t)(b * 1024 + kt * 64 + kl)) * 256 + dt * 64 + c4);
      t[kl][c4] = v.x; t[kl][c4 + 1] = v.y; t[kl][c4 + 2] = v.z; t[kl][c4 + 3] = v.w;
    }
    __syncthreads();
#pragma unroll
    for (int rr = 0; rr < 4; rr++) {
      const int dl = rr * 16 + r;
      ushort4 h;
      h.x = f2bf(t[c4][dl]);     h.y = f2bf(t[c4 + 1][dl]);
      h.z = f2bf(t[c4 + 2][dl]); h.w = f2bf(t[c4 + 3][dl]);
      *(ushort4*)(XT + ((size_t)(b * 256 + dt * 64 + dl)) * 1024 + kt * 64 + c4) = h;
    }
  } else {
    const int i = (bid - 82944) * 256 + threadIdx.x;
    if (i < 262144) {
      const int fI = i >> 8, d = i & 255;
      const int h = fI >> 8, ff = fI & 255;
      W1T[i] = f2bf(Wg1[((h << 8) + d) * 256 + ff]);
    } else if (i < 393216) {
      const int j = i - 262144;                 // t(1) | e'(7) | k(9)
      const int tt = j >> 16, rem = j & 65535;
      const int ep = rem >> 9, k = rem & 511;
      const int hh = ep >> 6;
      const float v = ((k >> 8) == hh)
          ? Wg2[(((tt * 2 + hh) << 8) + (k & 255)) * 64 + (ep & 63)] : 0.f;
      W2pT[j] = f2bf(v);
    } else if (i < 458752) {
      const int j = i - 393216;
      const int n = j >> 8, k = j & 255;
      Wf1T[j] = f2bf(Wf1[k * 256 + n]);
    } else if (i < 524288) {
      const int j = i - 458752;
      const int n = j >> 8, k = j & 255;
      Wf2T[j] = f2bf(Wf2[k * 256 + n]);
    }
  }
}

// ---------------- fused mid-chain: AX = adj@X -> h1 = relu(AX@W1+b) -> sup2 = W2p@h1^T ----------------
// Block = (mt: 64 adj-rows, bt = b*2+t). Grid (16,32) = 512 blocks, 2 blocks/CU (80 KB LDS).
// Phase-1 double-buffered: buf0 = {As[0], Bs}, buf1 = {As[1], AXs-region}; raw barriers.
__global__ __launch_bounds__(256, 2) void k_mid(const ushort_t* __restrict__ adjb,
                                                const ushort_t* __restrict__ XT,
                                                const ushort_t* __restrict__ W1T,
                                                const float* __restrict__ bg1,
                                                const ushort_t* __restrict__ W2pT,
                                                ushort_t* __restrict__ sup2T) {
  __shared__ __align__(16) ushort_t As[2][4096];   // 16 KB: phase1 A dbuf; phase3/4 B ping buffer
  __shared__ __align__(16) ushort_t Bs[16384];     // 32 KB: phase1 B buf0; lower 16K = phase3/4 B pong, upper = Hs
  __shared__ __align__(16) ushort_t AXs[16384];    // 32 KB: phase1 B buf1; then AX bf16 swizzled
  ushort_t* Hs = Bs + 8192;
  ushort_t* Asf = &As[0][0];

  const int mt = blockIdx.x, bt = blockIdx.y;
  const int b = bt >> 1, t = bt & 1;
  const int tid = threadIdx.x, wave = tid >> 6, lane = tid & 63;
  const int l15 = lane & 15, quad = lane >> 4;
  const int wm = wave >> 1, wn = wave & 1;
  const int srow8 = lane >> 3, schunk = lane & 7;
  const int gcol = (schunk ^ srow8) * 8;
  const int cx = l15 & 7;

  const ushort_t* gA = adjb + ((size_t)bt << 20) + (size_t)(mt * 64 + wave * 16 + srow8) * 1024 + gcol;
  const ushort_t* gB = XT + ((size_t)b << 18) + (size_t)(wave * 64 + srow8) * 1024 + gcol;
  ushort_t* lA0 = &As[0][0] + wave * 1024;
  ushort_t* lA1 = &As[1][0] + wave * 1024;
  ushort_t* lB0 = Bs + wave * 4096;
  ushort_t* lB1 = AXs + wave * 4096;

  floatx4 acc1[2][8] = {};
  const int arow1 = (wm * 32 + l15) * 64;
  const int brow1 = (wn * 128 + l15) * 64;

#define STAGE1(LA, LB, KOFF) do { \
  _Pragma("unroll") for (int ci = 0; ci < 2; ci++) gld16(gA + (size_t)(KOFF) + (size_t)(ci * 8) * 1024, (LA) + ci * 512); \
  _Pragma("unroll") for (int ci = 0; ci < 8; ci++) gld16(gB + (size_t)(KOFF) + (size_t)(ci * 8) * 1024, (LB) + ci * 512); \
} while (0)

#define MM1(AB, BB) do { \
  _Pragma("unroll") for (int ks = 0; ks < 2; ks++) { \
    const int cs = ((ks * 4 + quad) ^ cx) * 8; \
    short8 af[2], bfr[8]; \
    _Pragma("unroll") for (int i = 0; i < 2; i++) af[i]  = *(const short8*)((AB) + arow1 + i * 1024 + cs); \
    _Pragma("unroll") for (int j = 0; j < 8; j++) bfr[j] = *(const short8*)((BB) + brow1 + j * 1024 + cs); \
    _Pragma("unroll") for (int i = 0; i < 2; i++) \
      _Pragma("unroll") for (int j = 0; j < 8; j++) \
        acc1[i][j] = __builtin_amdgcn_mfma_f32_16x16x32_bf16(af[i], bfr[j], acc1[i][j], 0, 0, 0); \
  } \
} while (0)

  // ---- phase 1: AX(64x256) = adj @ X, K=1024; 2-phase prefetch ----
  STAGE1(lA0, lB0, 0);
  wait_bar();
#pragma unroll 1
  for (int k0 = 0; k0 < 1024; k0 += 128) {
    STAGE1(lA1, lB1, k0 + 64);           // prefetch odd tile
    MM1(&As[0][0], Bs);                  // compute even tile
    wait_bar();
    if (k0 + 128 < 1024) STAGE1(lA0, lB0, k0 + 128);  // prefetch next even tile
    MM1(&As[1][0], AXs);                 // compute odd tile
    wait_bar();
  }

#define STAGE3(DST, FG, KOFF) do { \
  _Pragma("unroll") for (int ci = 0; ci < 4; ci++) \
    gld16(W1T + (size_t)((FG) + wave * 32 + ci * 8 + srow8) * 256 + (KOFF) + gcol, (DST) + (wave * 32 + ci * 8) * 64); \
} while (0)

  STAGE3(Bs, t * 512, 0);   // prologue for nn=0, hides under phase 2

  // ---- phase 2: AX -> AXs (bf16, swizzled) ----
#pragma unroll
  for (int i = 0; i < 2; i++)
#pragma unroll
    for (int j = 0; j < 8; j++)
#pragma unroll
      for (int r = 0; r < 4; r++) {
        const int row = wm * 32 + i * 16 + quad * 4 + r;
        const int d   = wn * 128 + j * 16 + l15;
        AXs[row * 256 + ((((d >> 3) ^ row) & 31) << 3) + (d & 7)] = f2bf(acc1[i][j][r]);
      }
  __syncthreads();   // drains vmcnt too -> STAGE3 prologue complete

  floatx4 acc4[4][2] = {};   // sup2: 128 e' x 64 k' (wave-tile 64x32), persists over nn

#define MM3(BB, K0) do { \
  _Pragma("unroll") for (int ks = 0; ks < 2; ks++) { \
    const int c32 = ((K0) >> 3) + ks * 4 + quad; \
    const int cs = ((ks * 4 + quad) ^ cx) * 8; \
    short8 af[2], bfr[4]; \
    _Pragma("unroll") for (int i = 0; i < 2; i++) { \
      const int row = wm * 32 + i * 16 + l15; \
      af[i] = *(const short8*)(AXs + row * 256 + (((c32 ^ row) & 31) << 3)); \
    } \
    _Pragma("unroll") for (int j = 0; j < 4; j++) \
      bfr[j] = *(const short8*)((BB) + (wn * 64 + j * 16 + l15) * 64 + cs); \
    _Pragma("unroll") for (int i = 0; i < 2; i++) \
      _Pragma("unroll") for (int j = 0; j < 4; j++) \
        acc3[i][j] = __builtin_amdgcn_mfma_f32_16x16x32_bf16(af[i], bfr[j], acc3[i][j], 0, 0, 0); \
  } \
} while (0)

#define STAGE4(DST, KOFF) do { \
  _Pragma("unroll") for (int ci = 0; ci < 4; ci++) \
    gld16(W2pT + (size_t)t * 65536 + (size_t)(wave * 32 + ci * 8 + srow8) * 512 + nn * 128 + (KOFF) + gcol, \
          (DST) + (wave * 32 + ci * 8) * 64); \
} while (0)

#define MM4(BB, K0) do { \
  _Pragma("unroll") for (int ks = 0; ks < 2; ks++) { \
    const int c32h = ((K0) >> 3) + ks * 4 + quad; \
    const int cs = ((ks * 4 + quad) ^ cx) * 8; \
    short8 af[4], bfr[2]; \
    _Pragma("unroll") for (int i = 0; i < 4; i++) \
      af[i] = *(const short8*)((BB) + (wm * 64 + i * 16 + l15) * 64 + cs); \
    _Pragma("unroll") for (int j = 0; j < 2; j++) { \
      const int row = wn * 32 + j * 16 + l15; \
      bfr[j] = *(const short8*)(Hs + row * 128 + (((c32h ^ row) & 15) << 3)); \
    } \
    _Pragma("unroll") for (int i = 0; i < 4; i++) \
      _Pragma("unroll") for (int j = 0; j < 2; j++) \
        acc4[i][j] = __builtin_amdgcn_mfma_f32_16x16x32_bf16(af[i], bfr[j], acc4[i][j], 0, 0, 0); \
  } \
} while (0)

#pragma unroll 1
  for (int nn = 0; nn < 4; nn++) {
    const int fg = t * 512 + nn * 128;   // global feature base of this chunk
    floatx4 acc3[2][4] = {};

    // ---- phase 3: h1chunk(64 x 128) = relu(AXs @ W1T^T + bg1), K=256; ping-pong Bs-lower / Asf ----
    STAGE3(Asf, fg, 64);  MM3(Bs, 0);    wait_bar();
    STAGE3(Bs, fg, 128);  MM3(Asf, 64);  wait_bar();
    STAGE3(Asf, fg, 192); MM3(Bs, 128);  wait_bar();
    MM3(Asf, 192);
    STAGE4(Bs, 0);                       // phase-4 prologue, hides under relu epilogue

    // relu + bg1 -> Hs (64 x 128, swizzled mod 16)
#pragma unroll
    for (int j = 0; j < 4; j++) {
      const int fl = wn * 64 + j * 16 + l15;          // 0..127
      const float bj = bg1[fg + fl];
#pragma unroll
      for (int i = 0; i < 2; i++)
#pragma unroll
        for (int r = 0; r < 4; r++) {
          const int row = wm * 32 + i * 16 + quad * 4 + r;
          const float v = fmaxf(acc3[i][j][r] + bj, 0.f);
          Hs[row * 128 + ((((fl >> 3) ^ row) & 15) << 3) + (fl & 7)] = f2bf(v);
        }
    }
    __syncthreads();   // Hs visible + STAGE4 prologue drained + Asf readers done

    // ---- phase 4: acc4 += W2pT[t][:, nn*128..+128] @ h1chunk^T, K=128 ----
    STAGE4(Asf, 64);  MM4(Bs, 0);  wait_bar();
    MM4(Asf, 64);
    if (nn < 3) STAGE3(Bs, t * 512 + (nn + 1) * 128, 0);   // next nn's prologue
    wait_bar();
  }

  // ---- phase 5: write sup2T[b,t] (128 e' x cols mt*64..+64) ----
#pragma unroll
  for (int i = 0; i < 4; i++)
#pragma unroll
    for (int j = 0; j < 2; j++)
#pragma unroll
      for (int r = 0; r < 4; r++) {
        const int ep = wm * 64 + i * 16 + quad * 4 + r;
        const int kp = mt * 64 + wn * 32 + j * 16 + l15;
        sup2T[(size_t)bt * 131072 + (size_t)ep * 1024 + kp] = f2bf(acc4[i][j][r]);
      }
#undef STAGE1
#undef MM1
#undef STAGE3
#undef MM3
#undef STAGE4
#undef MM4
}

// ---------------- mega-tail: G4 + bias + LN + residual + FFN1 + relu + FFN2 + residual ----------------
// Block = 32 rows x 256 features, 4 waves side-by-side. Grid (32 mt, 16 b) = 512 blocks, 80 KB LDS.
__global__ __launch_bounds__(256, 2) void k_tail(const ushort_t* __restrict__ adjb,
                                                 const ushort_t* __restrict__ sup2T,
                                                 const float* __restrict__ bg2,
                                                 const float* __restrict__ gn,
                                                 const float* __restrict__ la,
                                                 const float* __restrict__ lb,
                                                 const ushort_t* __restrict__ Wf1T,
                                                 const float* __restrict__ bf1,
                                                 const ushort_t* __restrict__ Wf2T,
                                                 const float* __restrict__ bf2,
                                                 float* __restrict__ out) {
  __shared__ __align__(16) ushort_t SH[40960];   // 80 KB carved:
  ushort_t* A0  = SH;            // 8 KB: phase1 A buf0 (later sred/qred alias)
  ushort_t* A1  = SH + 4096;     // 8 KB: phase1 A buf1
  ushort_t* BsT = SH + 8192;     // 32 KB: phase1 B buf0; FFN W staging (per-wave private)
  ushort_t* PT  = SH + 24576;    // 32 KB: phase1 B buf1; later Ps(16K)+Ts(16K)
  ushort_t* Ps  = PT;
  ushort_t* Ts  = PT + 8192;
  float* sred = (float*)SH;          // [4][32] flattened
  float* qred = (float*)SH + 128;

  const int mt = blockIdx.x, b = blockIdx.y;
  const int tid = threadIdx.x, wave = tid >> 6, lane = tid & 63;
  const int l15 = lane & 15, quad = lane >> 4;
  const int wn = wave;
  const int tsel = wn >> 1;

  const int srow8 = lane >> 3, schunk = lane & 7;
  const int gcol = (schunk ^ srow8) * 8;

  const ushort_t* gA = adjb + ((size_t)(b * 2 + (wave >> 1)) << 20)
                     + (size_t)(mt * 32 + (wave & 1) * 16 + srow8) * 1024 + gcol;
  const ushort_t* gB = sup2T + (size_t)(b * 2 + (wave >> 1)) * 131072
                     + (size_t)((wave & 1) * 64 + srow8) * 1024 + gcol;
  ushort_t* lA0 = A0 + wave * 1024;
  ushort_t* lA1 = A1 + wave * 1024;
  ushort_t* lB0 = BsT + wave * 4096;
  ushort_t* lB1 = PT + wave * 4096;

  floatx4 acc[2][4] = {};
  const int arow0 = (tsel * 32 + l15) * 64;
  const int brow0 = (wn * 64 + l15) * 64;
  const int cx = l15 & 7;

#define TSTAGE1(LA, LB, KOFF) do { \
  _Pragma("unroll") for (int ci = 0; ci < 2; ci++) gld16(gA + (size_t)(KOFF) + (size_t)(ci * 8) * 1024, (LA) + ci * 512); \
  _Pragma("unroll") for (int ci = 0; ci < 8; ci++) gld16(gB + (size_t)(KOFF) + (size_t)(ci * 8) * 1024, (LB) + ci * 512); \
} while (0)

#define TMM1(AB, BB) do { \
  _Pragma("unroll") for (int ks = 0; ks < 2; ks++) { \
    const int cs = ((ks * 4 + quad) ^ cx) * 8; \
    short8 af[2], bfr[4]; \
    _Pragma("unroll") for (int i = 0; i < 2; i++) af[i]  = *(const short8*)((AB) + arow0 + i * 1024 + cs); \
    _Pragma("unroll") for (int j = 0; j < 4; j++) bfr[j] = *(const short8*)((BB) + brow0 + j * 1024 + cs); \
    _Pragma("unroll") for (int i = 0; i < 2; i++) \
      _Pragma("unroll") for (int j = 0; j < 4; j++) \
        acc[i][j] = __builtin_amdgcn_mfma_f32_16x16x32_bf16(af[i], bfr[j], acc[i][j], 0, 0, 0); \
  } \
} while (0)

  // ---- phase 1: G4 (adj @ sup2), K=1024; 2-phase prefetch ----
  TSTAGE1(lA0, lB0, 0);
  wait_bar();
#pragma unroll 1
  for (int k0 = 0; k0 < 1024; k0 += 128) {
    TSTAGE1(lA1, lB1, k0 + 64);
    TMM1(A0, BsT);
    wait_bar();
    if (k0 + 128 < 1024) TSTAGE1(lA0, lB0, k0 + 128);
    TMM1(A1, PT);
    wait_bar();
  }

#define TSTAGEF(W, DST, KOFF) do { \
  _Pragma("unroll") for (int ci = 0; ci < 8; ci++) \
    gld16((W) + (size_t)(wave * 64 + ci * 8 + srow8) * 256 + (KOFF) + gcol, (DST) + (wave * 64 + ci * 8) * 64); \
} while (0)

  TSTAGEF(Wf1T, BsT, 0);   // FFN1 prologue, hides under the LN reduction

  // ---- phase 2: bias + LN(ddof=1, eps on sd) + residual -> glnreg (f32) + Ps (bf16) ----
  float laj[4], lbj[4];
#pragma unroll
  for (int j = 0; j < 4; j++) {
    const int colg = wn * 64 + j * 16 + l15;
    const float bj = bg2[colg];
    laj[j] = la[colg]; lbj[j] = lb[colg];
#pragma unroll
    for (int i = 0; i < 2; i++)
#pragma unroll
      for (int r = 0; r < 4; r++) acc[i][j][r] += bj;
  }
#pragma unroll
  for (int i = 0; i < 2; i++)
#pragma unroll
    for (int r = 0; r < 4; r++) {
      float s = 0.f, q = 0.f;
#pragma unroll
      for (int j = 0; j < 4; j++) { const float v = acc[i][j][r]; s += v; q += v * v; }
#pragma unroll
      for (int m = 1; m < 16; m <<= 1) { s += __shfl_xor(s, m); q += __shfl_xor(q, m); }
      if (l15 == 0) {
        const int row = i * 16 + quad * 4 + r;
        sred[wn * 32 + row] = s; qred[wn * 32 + row] = q;
      }
    }
  __syncthreads();

  const size_t rowbase = (size_t)(b * 1024 + mt * 32);
  float glnreg[2][4][4];
#pragma unroll
  for (int i = 0; i < 2; i++)
#pragma unroll
    for (int r = 0; r < 4; r++) {
      const int row = i * 16 + quad * 4 + r;
      const float S = sred[row] + sred[32 + row] + sred[64 + row] + sred[96 + row];
      const float Q = qred[row] + qred[32 + row] + qred[64 + row] + qred[96 + row];
      const float mu = S * (1.f / 256.f);
      const float var = fmaxf((Q - S * mu) * (1.f / 255.f), 0.f);
      const float inv = 1.f / (sqrtf(var) + 1e-6f);
      const float* gnr = gn + (rowbase + row) * 256;
#pragma unroll
      for (int j = 0; j < 4; j++) {
        const int colg = wn * 64 + j * 16 + l15;
        const float g = laj[j] * (acc[i][j][r] - mu) * inv + lbj[j] + gnr[colg];
        glnreg[i][j][r] = g;
        Ps[row * 256 + ((((colg >> 3) ^ row) & 31) << 3) + (colg & 7)] = f2bf(g);
      }
    }
  __syncthreads();   // Ps visible; drains vmcnt -> FFN1 tile0 ready

  // ---- phase 3: FFN GEMM1: t = relu(gln @ Wf1 + bf1), K=256 ----
  // Barrier-free: each wave stages & reads only its own 64-row slice of BsT.
  floatx4 acc2[2][4] = {};
#pragma unroll 1
  for (int k0 = 0; k0 < 256; k0 += 64) {
    vwait0();                               // own stage (prev iter) landed in LDS
    short8 af[2][2], bfr[2][4];
#pragma unroll
    for (int ks = 0; ks < 2; ks++) {
      const int c32 = (k0 >> 3) + ks * 4 + quad;
      const int cs = ((ks * 4 + quad) ^ cx) * 8;
#pragma unroll
      for (int i = 0; i < 2; i++) {
        const int row = i * 16 + l15;
        af[ks][i] = *(const short8*)(Ps + row * 256 + (((c32 ^ row) & 31) << 3));
      }
#pragma unroll
      for (int j = 0; j < 4; j++)
        bfr[ks][j] = *(const short8*)(BsT + brow0 + j * 1024 + cs);
    }
    lwait0();                               // frags in regs -> safe to overwrite own slice
    if (k0 < 192) TSTAGEF(Wf1T, BsT, k0 + 64);
#pragma unroll
    for (int ks = 0; ks < 2; ks++)
#pragma unroll
      for (int i = 0; i < 2; i++)
#pragma unroll
        for (int j = 0; j < 4; j++)
          acc2[i][j] = __builtin_amdgcn_mfma_f32_16x16x32_bf16(af[ks][i], bfr[ks][j], acc2[i][j], 0, 0, 0);
  }

  TSTAGEF(Wf2T, BsT, 0);   // FFN2 prologue, hides under relu epilogue

  // ---- phase 4: relu + bf1 -> Ts ----
#pragma unroll
  for (int j = 0; j < 4; j++) {
    const int colg = wn * 64 + j * 16 + l15;
    const float bj = bf1[colg];
#pragma unroll
    for (int i = 0; i < 2; i++)
#pragma unroll
      for (int r = 0; r < 4; r++) {
        const int row = i * 16 + quad * 4 + r;
        const float v = fmaxf(acc2[i][j][r] + bj, 0.f);
        Ts[row * 256 + ((((colg >> 3) ^ row) & 31) << 3) + (colg & 7)] = f2bf(v);
      }
  }
  __syncthreads();   // Ts visible; drains vmcnt -> FFN2 tile0 ready

  // ---- phase 5: FFN GEMM2: out = t @ Wf2 + bf2 + gln, K=256, barrier-free ----
  floatx4 acc3f[2][4] = {};
#pragma unroll 1
  for (int k0 = 0; k0 < 256; k0 += 64) {
    vwait0();
    short8 af[2][2], bfr[2][4];
#pragma unroll
    for (int ks = 0; ks < 2; ks++) {
      const int c32 = (k0 >> 3) + ks * 4 + quad;
      const int cs = ((ks * 4 + quad) ^ cx) * 8;
#pragma unroll
      for (int i = 0; i < 2; i++) {
        const int row = i * 16 + l15;
        af[ks][i] = *(const short8*)(Ts + row * 256 + (((c32 ^ row) & 31) << 3));
      }
#pragma unroll
      for (int j = 0; j < 4; j++)
        bfr[ks][j] = *(const short8*)(BsT + brow0 + j * 1024 + cs);
    }
    lwait0();
    if (k0 < 192) TSTAGEF(Wf2T, BsT, k0 + 64);
#pragma unroll
    for (int ks = 0; ks < 2; ks++)
#pragma unroll
      for (int i = 0; i < 2; i++)
#pragma unroll
        for (int j = 0; j < 4; j++)
          acc3f[i][j] = __builtin_amdgcn_mfma_f32_16x16x32_bf16(af[ks][i], bfr[ks][j], acc3f[i][j], 0, 0, 0);
  }

  // ---- phase 6: + bf2 + gln residual (f32), write out (nontemporal) ----
#pragma unroll
  for (int j = 0; j < 4; j++) {
    const int colg = wn * 64 + j * 16 + l15;
    const float bj = bf2[colg];
#pragma unroll
    for (int i = 0; i < 2; i++)
#pragma unroll
      for (int r = 0; r < 4; r++) {
        const int row = i * 16 + quad * 4 + r;
        __builtin_nontemporal_store(acc3f[i][j][r] + bj + glnreg[i][j][r],
                                    &out[(rowbase + row) * 256 + colg]);
      }
  }
#undef TSTAGE1
#undef TMM1
#undef TSTAGEF
}

extern "C" void kernel_launch(void* const* d_in, const int* in_sizes, int n_in,
                              void* d_out, int out_size, void* d_ws, size_t ws_size,
                              hipStream_t stream) {
  const float* gnodes = (const float*)d_in[0];
  const int*   graph  = (const int*)d_in[1];
  const float* Wg1 = (const float*)d_in[2];
  const float* bg1 = (const float*)d_in[3];
  const float* Wg2 = (const float*)d_in[4];
  const float* bg2 = (const float*)d_in[5];
  const float* Wf1 = (const float*)d_in[6];
  const float* bf1 = (const float*)d_in[7];
  const float* Wf2 = (const float*)d_in[8];
  const float* bf2 = (const float*)d_in[9];
  const float* ln_a = (const float*)d_in[10];
  const float* ln_b = (const float*)d_in[11];

  float* adj_out = (float*)d_out;
  float* out     = (float*)d_out + 83886080;   // (16,5,1024,1024) f32 first

  char* ws = (char*)d_ws;
  ushort_t* adjb  = (ushort_t*)(ws);                       //  67108864 B (16,2,1024,1024)
  ushort_t* XT    = (ushort_t*)(ws + 67108864);            //   8388608 B (16,256,1024)
  ushort_t* W1T   = (ushort_t*)(ws + 75497472);            //    524288 B
  ushort_t* W2pT  = (ushort_t*)(ws + 76021760);            //    262144 B (2,128,512)
  ushort_t* Wf1T  = (ushort_t*)(ws + 76283904);            //    131072 B
  ushort_t* Wf2T  = (ushort_t*)(ws + 76414976);            //    131072 B
  ushort_t* sup2T = (ushort_t*)(ws + 76546048);            //   8388608 B (16,2,128,1024)

  k_prep<<<84992, 256, 0, stream>>>(graph, adj_out, adjb, gnodes, XT,
                                    Wg1, Wg2, Wf1, Wf2, W1T, W2pT, Wf1T, Wf2T);

  k_mid<<<dim3(16, 32), 256, 0, stream>>>(adjb, XT, W1T, bg1, W2pT, sup2T);

  k_tail<<<dim3(32, 16), 256, 0, stream>>>(adjb, sup2T, bg2, gnodes, ln_a, ln_b,
                                           Wf1T, bf1, Wf2T, bf2, out);
}

// Round 2
// 630.510 us; speedup vs baseline: 1.0413x; 1.0126x over previous
//
#include <hip/hip_runtime.h>

typedef unsigned short ushort_t;
using short8  = __attribute__((ext_vector_type(8))) short;
using floatx4 = __attribute__((ext_vector_type(4))) float;
using intx4   = __attribute__((ext_vector_type(4))) int;
using fx4     = __attribute__((ext_vector_type(4))) float;

__device__ __forceinline__ ushort_t f2bf(float f) {
  unsigned int x = __builtin_bit_cast(unsigned int, f);
  x += 0x7fffu + ((x >> 16) & 1u);           // RNE
  return (ushort_t)(x >> 16);
}

__device__ __forceinline__ void gld16(const ushort_t* g, ushort_t* l) {
  __builtin_amdgcn_global_load_lds(
      (const __attribute__((address_space(1))) void*)(unsigned long long)(uintptr_t)g,
      (__attribute__((address_space(3))) void*)l, 16, 0, 0);
}

// vmcnt(0) drain + workgroup barrier (raw: does NOT drain prefetches issued after)
__device__ __forceinline__ void wait_bar() {
  asm volatile("s_waitcnt vmcnt(0)" ::: "memory");
  __builtin_amdgcn_s_barrier();
  __builtin_amdgcn_sched_barrier(0);
}
__device__ __forceinline__ void vwait0() {
  asm volatile("s_waitcnt vmcnt(0)" ::: "memory");
  __builtin_amdgcn_sched_barrier(0);
}
__device__ __forceinline__ void lwait0() {
  asm volatile("s_waitcnt lgkmcnt(0)" ::: "memory");
  __builtin_amdgcn_sched_barrier(0);
}

// ---------------- merged prep kernel ----------------
// blocks [0, 81920): adj cast (f32 out + bf16 slices 1,4) — nontemporal stream
// blocks [81920, 82944): X transpose -> XT bf16
// blocks [82944, 84992): weight prep
__global__ __launch_bounds__(256) void k_prep(const int* __restrict__ graph,
                                              float* __restrict__ adj_out,
                                              ushort_t* __restrict__ adjb,
                                              const float* __restrict__ gn,
                                              ushort_t* __restrict__ XT,
                                              const float* __restrict__ Wg1, const float* __restrict__ Wg2,
                                              const float* __restrict__ Wf1, const float* __restrict__ Wf2,
                                              ushort_t* __restrict__ W1T, ushort_t* __restrict__ W2pT,
                                              ushort_t* __restrict__ Wf1T, ushort_t* __restrict__ Wf2T) {
  __shared__ float t[64][68];
  const int bid = blockIdx.x;
  if (bid < 81920) {
    const size_t i = (size_t)bid * 256 + threadIdx.x;   // int4 index
    intx4 v = __builtin_nontemporal_load((const intx4*)graph + i);
    fx4 f; f[0] = (float)v[0]; f[1] = (float)v[1]; f[2] = (float)v[2]; f[3] = (float)v[3];
    __builtin_nontemporal_store(f, (fx4*)adj_out + i);
    const size_t e0 = i * 4;
    const unsigned sb = (unsigned)(e0 >> 20);
    const unsigned s = sb % 5u, b = sb / 5u;
    if (s == 1u || s == 4u) {
      const unsigned tt = (s == 4u) ? 1u : 0u;
      ushort4 h;
      h.x = f2bf(f[0]); h.y = f2bf(f[1]); h.z = f2bf(f[2]); h.w = f2bf(f[3]);
      *(ushort4*)(adjb + (((size_t)(b * 2 + tt)) << 20) + (e0 & 0xFFFFFu)) = h;
    }
  } else if (bid < 82944) {
    const int id = bid - 81920;
    const int kt = id & 15, dt = (id >> 4) & 3, b = id >> 6;
    const int r  = threadIdx.x >> 4;
    const int c4 = (threadIdx.x & 15) * 4;
#pragma unroll
    for (int rr = 0; rr < 4; rr++) {
      const int kl = rr * 16 + r;
      float4 v = *(const float4*)(gn + ((size_t)(b * 1024 + kt * 64 + kl)) * 256 + dt * 64 + c4);
      t[kl][c4] = v.x; t[kl][c4 + 1] = v.y; t[kl][c4 + 2] = v.z; t[kl][c4 + 3] = v.w;
    }
    __syncthreads();
#pragma unroll
    for (int rr = 0; rr < 4; rr++) {
      const int dl = rr * 16 + r;
      ushort4 h;
      h.x = f2bf(t[c4][dl]);     h.y = f2bf(t[c4 + 1][dl]);
      h.z = f2bf(t[c4 + 2][dl]); h.w = f2bf(t[c4 + 3][dl]);
      *(ushort4*)(XT + ((size_t)(b * 256 + dt * 64 + dl)) * 1024 + kt * 64 + c4) = h;
    }
  } else {
    const int i = (bid - 82944) * 256 + threadIdx.x;
    if (i < 262144) {
      const int fI = i >> 8, d = i & 255;
      const int h = fI >> 8, ff = fI & 255;
      W1T[i] = f2bf(Wg1[((h << 8) + d) * 256 + ff]);
    } else if (i < 393216) {
      const int j = i - 262144;                 // t(1) | e'(7) | k(9)
      const int tt = j >> 16, rem = j & 65535;
      const int ep = rem >> 9, k = rem & 511;
      const int hh = ep >> 6;
      const float v = ((k >> 8) == hh)
          ? Wg2[(((tt * 2 + hh) << 8) + (k & 255)) * 64 + (ep & 63)] : 0.f;
      W2pT[j] = f2bf(v);
    } else if (i < 458752) {
      const int j = i - 393216;
      const int n = j >> 8, k = j & 255;
      Wf1T[j] = f2bf(Wf1[k * 256 + n]);
    } else if (i < 524288) {
      const int j = i - 458752;
      const int n = j >> 8, k = j & 255;
      Wf2T[j] = f2bf(Wf2[k * 256 + n]);
    }
  }
}

// ---------------- fused mid-chain: AX = adj@X -> h1 = relu(AX@W1+b) -> sup2 = W2p@h1^T ----------------
// 1D grid of 512 blocks, XCD-locked by b: xcd = wgid&7, b = xcd + 8*(slot>>5).
// All 32 blocks sharing b live on one XCD -> XT[b] (512 KB) is L2-resident.
__global__ __launch_bounds__(256, 2) void k_mid(const ushort_t* __restrict__ adjb,
                                                const ushort_t* __restrict__ XT,
                                                const ushort_t* __restrict__ W1T,
                                                const float* __restrict__ bg1,
                                                const ushort_t* __restrict__ W2pT,
                                                ushort_t* __restrict__ sup2T) {
  __shared__ __align__(16) ushort_t As[2][4096];   // 16 KB: phase1 A dbuf; phase3/4 B ping buffer
  __shared__ __align__(16) ushort_t Bs[16384];     // 32 KB: phase1 B buf0; lower 16K = phase3/4 B pong, upper = Hs
  __shared__ __align__(16) ushort_t AXs[16384];    // 32 KB: phase1 B buf1; then AX bf16 swizzled
  ushort_t* Hs = Bs + 8192;
  ushort_t* Asf = &As[0][0];

  // XCD-locked decomposition
  const int wgid = blockIdx.x;
  const int xcd = wgid & 7, slot = wgid >> 3;
  const int b = ((slot >> 5) << 3) | xcd;
  const int sub = slot & 31;
  const int t = sub >> 4, mt = sub & 15;
  const int bt = b * 2 + t;

  const int tid = threadIdx.x, wave = tid >> 6, lane = tid & 63;
  const int l15 = lane & 15, quad = lane >> 4;
  const int wm = wave >> 1, wn = wave & 1;
  const int srow8 = lane >> 3, schunk = lane & 7;
  const int gcol = (schunk ^ srow8) * 8;
  const int cx = l15 & 7;

  const ushort_t* gA = adjb + ((size_t)bt << 20) + (size_t)(mt * 64 + wave * 16 + srow8) * 1024 + gcol;
  const ushort_t* gB = XT + ((size_t)b << 18) + (size_t)(wave * 64 + srow8) * 1024 + gcol;
  ushort_t* lA0 = &As[0][0] + wave * 1024;
  ushort_t* lA1 = &As[1][0] + wave * 1024;
  ushort_t* lB0 = Bs + wave * 4096;
  ushort_t* lB1 = AXs + wave * 4096;

  floatx4 acc1[2][8] = {};
  const int arow1 = (wm * 32 + l15) * 64;
  const int brow1 = (wn * 128 + l15) * 64;

#define STAGE1(LA, LB, KOFF) do { \
  _Pragma("unroll") for (int ci = 0; ci < 2; ci++) gld16(gA + (size_t)(KOFF) + (size_t)(ci * 8) * 1024, (LA) + ci * 512); \
  _Pragma("unroll") for (int ci = 0; ci < 8; ci++) gld16(gB + (size_t)(KOFF) + (size_t)(ci * 8) * 1024, (LB) + ci * 512); \
} while (0)

#define MM1(AB, BB) do { \
  _Pragma("unroll") for (int ks = 0; ks < 2; ks++) { \
    const int cs = ((ks * 4 + quad) ^ cx) * 8; \
    short8 af[2], bfr[8]; \
    _Pragma("unroll") for (int i = 0; i < 2; i++) af[i]  = *(const short8*)((AB) + arow1 + i * 1024 + cs); \
    _Pragma("unroll") for (int j = 0; j < 8; j++) bfr[j] = *(const short8*)((BB) + brow1 + j * 1024 + cs); \
    _Pragma("unroll") for (int i = 0; i < 2; i++) \
      _Pragma("unroll") for (int j = 0; j < 8; j++) \
        acc1[i][j] = __builtin_amdgcn_mfma_f32_16x16x32_bf16(af[i], bfr[j], acc1[i][j], 0, 0, 0); \
  } \
} while (0)

  // ---- phase 1: AX(64x256) = adj @ X, K=1024; 2-phase prefetch ----
  STAGE1(lA0, lB0, 0);
  wait_bar();
#pragma unroll 1
  for (int k0 = 0; k0 < 1024; k0 += 128) {
    STAGE1(lA1, lB1, k0 + 64);           // prefetch odd tile
    MM1(&As[0][0], Bs);                  // compute even tile
    wait_bar();
    if (k0 + 128 < 1024) STAGE1(lA0, lB0, k0 + 128);  // prefetch next even tile
    MM1(&As[1][0], AXs);                 // compute odd tile
    wait_bar();
  }

#define STAGE3(DST, FG, KOFF) do { \
  _Pragma("unroll") for (int ci = 0; ci < 4; ci++) \
    gld16(W1T + (size_t)((FG) + wave * 32 + ci * 8 + srow8) * 256 + (KOFF) + gcol, (DST) + (wave * 32 + ci * 8) * 64); \
} while (0)

  STAGE3(Bs, t * 512, 0);   // prologue for nn=0, hides under phase 2

  // ---- phase 2: AX -> AXs (bf16, swizzled) ----
#pragma unroll
  for (int i = 0; i < 2; i++)
#pragma unroll
    for (int j = 0; j < 8; j++)
#pragma unroll
      for (int r = 0; r < 4; r++) {
        const int row = wm * 32 + i * 16 + quad * 4 + r;
        const int d   = wn * 128 + j * 16 + l15;
        AXs[row * 256 + ((((d >> 3) ^ row) & 31) << 3) + (d & 7)] = f2bf(acc1[i][j][r]);
      }
  __syncthreads();   // drains vmcnt too -> STAGE3 prologue complete

  floatx4 acc4[4][2] = {};   // sup2: 128 e' x 64 k' (wave-tile 64x32), persists over nn

#define MM3(BB, K0) do { \
  _Pragma("unroll") for (int ks = 0; ks < 2; ks++) { \
    const int c32 = ((K0) >> 3) + ks * 4 + quad; \
    const int cs = ((ks * 4 + quad) ^ cx) * 8; \
    short8 af[2], bfr[4]; \
    _Pragma("unroll") for (int i = 0; i < 2; i++) { \
      const int row = wm * 32 + i * 16 + l15; \
      af[i] = *(const short8*)(AXs + row * 256 + (((c32 ^ row) & 31) << 3)); \
    } \
    _Pragma("unroll") for (int j = 0; j < 4; j++) \
      bfr[j] = *(const short8*)((BB) + (wn * 64 + j * 16 + l15) * 64 + cs); \
    _Pragma("unroll") for (int i = 0; i < 2; i++) \
      _Pragma("unroll") for (int j = 0; j < 4; j++) \
        acc3[i][j] = __builtin_amdgcn_mfma_f32_16x16x32_bf16(af[i], bfr[j], acc3[i][j], 0, 0, 0); \
  } \
} while (0)

#define STAGE4(DST, KOFF) do { \
  _Pragma("unroll") for (int ci = 0; ci < 4; ci++) \
    gld16(W2pT + (size_t)t * 65536 + (size_t)(wave * 32 + ci * 8 + srow8) * 512 + nn * 128 + (KOFF) + gcol, \
          (DST) + (wave * 32 + ci * 8) * 64); \
} while (0)

#define MM4(BB, K0) do { \
  _Pragma("unroll") for (int ks = 0; ks < 2; ks++) { \
    const int c32h = ((K0) >> 3) + ks * 4 + quad; \
    const int cs = ((ks * 4 + quad) ^ cx) * 8; \
    short8 af[4], bfr[2]; \
    _Pragma("unroll") for (int i = 0; i < 4; i++) \
      af[i] = *(const short8*)((BB) + (wm * 64 + i * 16 + l15) * 64 + cs); \
    _Pragma("unroll") for (int j = 0; j < 2; j++) { \
      const int row = wn * 32 + j * 16 + l15; \
      bfr[j] = *(const short8*)(Hs + row * 128 + (((c32h ^ row) & 15) << 3)); \
    } \
    _Pragma("unroll") for (int i = 0; i < 4; i++) \
      _Pragma("unroll") for (int j = 0; j < 2; j++) \
        acc4[i][j] = __builtin_amdgcn_mfma_f32_16x16x32_bf16(af[i], bfr[j], acc4[i][j], 0, 0, 0); \
  } \
} while (0)

#pragma unroll 1
  for (int nn = 0; nn < 4; nn++) {
    const int fg = t * 512 + nn * 128;   // global feature base of this chunk
    floatx4 acc3[2][4] = {};

    // ---- phase 3: h1chunk(64 x 128) = relu(AXs @ W1T^T + bg1), K=256; ping-pong Bs-lower / Asf ----
    STAGE3(Asf, fg, 64);  MM3(Bs, 0);    wait_bar();
    STAGE3(Bs, fg, 128);  MM3(Asf, 64);  wait_bar();
    STAGE3(Asf, fg, 192); MM3(Bs, 128);  wait_bar();
    MM3(Asf, 192);
    STAGE4(Bs, 0);                       // phase-4 prologue, hides under relu epilogue

    // relu + bg1 -> Hs (64 x 128, swizzled mod 16)
#pragma unroll
    for (int j = 0; j < 4; j++) {
      const int fl = wn * 64 + j * 16 + l15;          // 0..127
      const float bj = bg1[fg + fl];
#pragma unroll
      for (int i = 0; i < 2; i++)
#pragma unroll
        for (int r = 0; r < 4; r++) {
          const int row = wm * 32 + i * 16 + quad * 4 + r;
          const float v = fmaxf(acc3[i][j][r] + bj, 0.f);
          Hs[row * 128 + ((((fl >> 3) ^ row) & 15) << 3) + (fl & 7)] = f2bf(v);
        }
    }
    __syncthreads();   // Hs visible + STAGE4 prologue drained + Asf readers done

    // ---- phase 4: acc4 += W2pT[t][:, nn*128..+128] @ h1chunk^T, K=128 ----
    // W2pT is block-diagonal: chunk nn only touches e'-half (nn>>1); other waves' MFMAs
    // would multiply exact zeros -> skip (bit-exact).
    const int act4 = (wm == (nn >> 1));
    STAGE4(Asf, 64);
    if (act4) MM4(Bs, 0);
    wait_bar();
    if (act4) MM4(Asf, 64);
    if (nn < 3) STAGE3(Bs, t * 512 + (nn + 1) * 128, 0);   // next nn's prologue
    wait_bar();
  }

  // ---- phase 5: write sup2T[b,t] (128 e' x cols mt*64..+64) ----
#pragma unroll
  for (int i = 0; i < 4; i++)
#pragma unroll
    for (int j = 0; j < 2; j++)
#pragma unroll
      for (int r = 0; r < 4; r++) {
        const int ep = wm * 64 + i * 16 + quad * 4 + r;
        const int kp = mt * 64 + wn * 32 + j * 16 + l15;
        sup2T[(size_t)bt * 131072 + (size_t)ep * 1024 + kp] = f2bf(acc4[i][j][r]);
      }
#undef STAGE1
#undef MM1
#undef STAGE3
#undef MM3
#undef STAGE4
#undef MM4
}

// ---------------- mega-tail: G4 + bias + LN + residual + FFN1 + relu + FFN2 + residual ----------------
// 1D grid of 512 blocks, XCD-locked by b (sup2T[b] 512 KB + gn slices L2-resident per XCD).
__global__ __launch_bounds__(256, 2) void k_tail(const ushort_t* __restrict__ adjb,
                                                 const ushort_t* __restrict__ sup2T,
                                                 const float* __restrict__ bg2,
                                                 const float* __restrict__ gn,
                                                 const float* __restrict__ la,
                                                 const float* __restrict__ lb,
                                                 const ushort_t* __restrict__ Wf1T,
                                                 const float* __restrict__ bf1,
                                                 const ushort_t* __restrict__ Wf2T,
                                                 const float* __restrict__ bf2,
                                                 float* __restrict__ out) {
  __shared__ __align__(16) ushort_t SH[40960];   // 80 KB carved:
  ushort_t* A0  = SH;            // 8 KB: phase1 A buf0 (later sred/qred alias)
  ushort_t* A1  = SH + 4096;     // 8 KB: phase1 A buf1
  ushort_t* BsT = SH + 8192;     // 32 KB: phase1 B buf0; FFN W staging (per-wave private)
  ushort_t* PT  = SH + 24576;    // 32 KB: phase1 B buf1; later Ps(16K)+Ts(16K)
  ushort_t* Ps  = PT;
  ushort_t* Ts  = PT + 8192;
  float* sred = (float*)SH;          // [4][32] flattened
  float* qred = (float*)SH + 128;

  // XCD-locked decomposition
  const int wgid = blockIdx.x;
  const int xcd = wgid & 7, slot = wgid >> 3;
  const int b = ((slot >> 5) << 3) | xcd;
  const int mt = slot & 31;

  const int tid = threadIdx.x, wave = tid >> 6, lane = tid & 63;
  const int l15 = lane & 15, quad = lane >> 4;
  const int wn = wave;
  const int tsel = wn >> 1;

  const int srow8 = lane >> 3, schunk = lane & 7;
  const int gcol = (schunk ^ srow8) * 8;

  const ushort_t* gA = adjb + ((size_t)(b * 2 + (wave >> 1)) << 20)
                     + (size_t)(mt * 32 + (wave & 1) * 16 + srow8) * 1024 + gcol;
  const ushort_t* gB = sup2T + (size_t)(b * 2 + (wave >> 1)) * 131072
                     + (size_t)((wave & 1) * 64 + srow8) * 1024 + gcol;
  ushort_t* lA0 = A0 + wave * 1024;
  ushort_t* lA1 = A1 + wave * 1024;
  ushort_t* lB0 = BsT + wave * 4096;
  ushort_t* lB1 = PT + wave * 4096;

  floatx4 acc[2][4] = {};
  const int arow0 = (tsel * 32 + l15) * 64;
  const int brow0 = (wn * 64 + l15) * 64;
  const int cx = l15 & 7;

#define TSTAGE1(LA, LB, KOFF) do { \
  _Pragma("unroll") for (int ci = 0; ci < 2; ci++) gld16(gA + (size_t)(KOFF) + (size_t)(ci * 8) * 1024, (LA) + ci * 512); \
  _Pragma("unroll") for (int ci = 0; ci < 8; ci++) gld16(gB + (size_t)(KOFF) + (size_t)(ci * 8) * 1024, (LB) + ci * 512); \
} while (0)

#define TMM1(AB, BB) do { \
  _Pragma("unroll") for (int ks = 0; ks < 2; ks++) { \
    const int cs = ((ks * 4 + quad) ^ cx) * 8; \
    short8 af[2], bfr[4]; \
    _Pragma("unroll") for (int i = 0; i < 2; i++) af[i]  = *(const short8*)((AB) + arow0 + i * 1024 + cs); \
    _Pragma("unroll") for (int j = 0; j < 4; j++) bfr[j] = *(const short8*)((BB) + brow0 + j * 1024 + cs); \
    _Pragma("unroll") for (int i = 0; i < 2; i++) \
      _Pragma("unroll") for (int j = 0; j < 4; j++) \
        acc[i][j] = __builtin_amdgcn_mfma_f32_16x16x32_bf16(af[i], bfr[j], acc[i][j], 0, 0, 0); \
  } \
} while (0)

  // ---- phase 1: G4 (adj @ sup2), K=1024; 2-phase prefetch ----
  TSTAGE1(lA0, lB0, 0);
  wait_bar();
#pragma unroll 1
  for (int k0 = 0; k0 < 1024; k0 += 128) {
    TSTAGE1(lA1, lB1, k0 + 64);
    TMM1(A0, BsT);
    wait_bar();
    if (k0 + 128 < 1024) TSTAGE1(lA0, lB0, k0 + 128);
    TMM1(A1, PT);
    wait_bar();
  }

#define TSTAGEF(W, DST, KOFF) do { \
  _Pragma("unroll") for (int ci = 0; ci < 8; ci++) \
    gld16((W) + (size_t)(wave * 64 + ci * 8 + srow8) * 256 + (KOFF) + gcol, (DST) + (wave * 64 + ci * 8) * 64); \
} while (0)

  TSTAGEF(Wf1T, BsT, 0);   // FFN1 prologue, hides under the LN reduction

  // ---- phase 2: bias + LN(ddof=1, eps on sd) + residual -> glnreg (f32) + Ps (bf16) ----
  float laj[4], lbj[4];
#pragma unroll
  for (int j = 0; j < 4; j++) {
    const int colg = wn * 64 + j * 16 + l15;
    const float bj = bg2[colg];
    laj[j] = la[colg]; lbj[j] = lb[colg];
#pragma unroll
    for (int i = 0; i < 2; i++)
#pragma unroll
      for (int r = 0; r < 4; r++) acc[i][j][r] += bj;
  }
#pragma unroll
  for (int i = 0; i < 2; i++)
#pragma unroll
    for (int r = 0; r < 4; r++) {
      float s = 0.f, q = 0.f;
#pragma unroll
      for (int j = 0; j < 4; j++) { const float v = acc[i][j][r]; s += v; q += v * v; }
#pragma unroll
      for (int m = 1; m < 16; m <<= 1) { s += __shfl_xor(s, m); q += __shfl_xor(q, m); }
      if (l15 == 0) {
        const int row = i * 16 + quad * 4 + r;
        sred[wn * 32 + row] = s; qred[wn * 32 + row] = q;
      }
    }
  __syncthreads();

  const size_t rowbase = (size_t)(b * 1024 + mt * 32);
  float glnreg[2][4][4];
#pragma unroll
  for (int i = 0; i < 2; i++)
#pragma unroll
    for (int r = 0; r < 4; r++) {
      const int row = i * 16 + quad * 4 + r;
      const float S = sred[row] + sred[32 + row] + sred[64 + row] + sred[96 + row];
      const float Q = qred[row] + qred[32 + row] + qred[64 + row] + qred[96 + row];
      const float mu = S * (1.f / 256.f);
      const float var = fmaxf((Q - S * mu) * (1.f / 255.f), 0.f);
      const float inv = 1.f / (sqrtf(var) + 1e-6f);
      const float* gnr = gn + (rowbase + row) * 256;
#pragma unroll
      for (int j = 0; j < 4; j++) {
        const int colg = wn * 64 + j * 16 + l15;
        const float g = laj[j] * (acc[i][j][r] - mu) * inv + lbj[j] + gnr[colg];
        glnreg[i][j][r] = g;
        Ps[row * 256 + ((((colg >> 3) ^ row) & 31) << 3) + (colg & 7)] = f2bf(g);
      }
    }
  __syncthreads();   // Ps visible; drains vmcnt -> FFN1 tile0 ready

  // ---- phase 3: FFN GEMM1: t = relu(gln @ Wf1 + bf1), K=256 ----
  // Barrier-free: each wave stages & reads only its own 64-row slice of BsT.
  floatx4 acc2[2][4] = {};
#pragma unroll 1
  for (int k0 = 0; k0 < 256; k0 += 64) {
    vwait0();                               // own stage (prev iter) landed in LDS
    short8 af[2][2], bfr[2][4];
#pragma unroll
    for (int ks = 0; ks < 2; ks++) {
      const int c32 = (k0 >> 3) + ks * 4 + quad;
      const int cs = ((ks * 4 + quad) ^ cx) * 8;
#pragma unroll
      for (int i = 0; i < 2; i++) {
        const int row = i * 16 + l15;
        af[ks][i] = *(const short8*)(Ps + row * 256 + (((c32 ^ row) & 31) << 3));
      }
#pragma unroll
      for (int j = 0; j < 4; j++)
        bfr[ks][j] = *(const short8*)(BsT + brow0 + j * 1024 + cs);
    }
    lwait0();                               // frags in regs -> safe to overwrite own slice
    if (k0 < 192) TSTAGEF(Wf1T, BsT, k0 + 64);
#pragma unroll
    for (int ks = 0; ks < 2; ks++)
#pragma unroll
      for (int i = 0; i < 2; i++)
#pragma unroll
        for (int j = 0; j < 4; j++)
          acc2[i][j] = __builtin_amdgcn_mfma_f32_16x16x32_bf16(af[ks][i], bfr[ks][j], acc2[i][j], 0, 0, 0);
  }

  TSTAGEF(Wf2T, BsT, 0);   // FFN2 prologue, hides under relu epilogue

  // ---- phase 4: relu + bf1 -> Ts ----
#pragma unroll
  for (int j = 0; j < 4; j++) {
    const int colg = wn * 64 + j * 16 + l15;
    const float bj = bf1[colg];
#pragma unroll
    for (int i = 0; i < 2; i++)
#pragma unroll
      for (int r = 0; r < 4; r++) {
        const int row = i * 16 + quad * 4 + r;
        const float v = fmaxf(acc2[i][j][r] + bj, 0.f);
        Ts[row * 256 + ((((colg >> 3) ^ row) & 31) << 3) + (colg & 7)] = f2bf(v);
      }
  }
  __syncthreads();   // Ts visible; drains vmcnt -> FFN2 tile0 ready

  // ---- phase 5: FFN GEMM2: out = t @ Wf2 + bf2 + gln, K=256, barrier-free ----
  floatx4 acc3f[2][4] = {};
#pragma unroll 1
  for (int k0 = 0; k0 < 256; k0 += 64) {
    vwait0();
    short8 af[2][2], bfr[2][4];
#pragma unroll
    for (int ks = 0; ks < 2; ks++) {
      const int c32 = (k0 >> 3) + ks * 4 + quad;
      const int cs = ((ks * 4 + quad) ^ cx) * 8;
#pragma unroll
      for (int i = 0; i < 2; i++) {
        const int row = i * 16 + l15;
        af[ks][i] = *(const short8*)(Ts + row * 256 + (((c32 ^ row) & 31) << 3));
      }
#pragma unroll
      for (int j = 0; j < 4; j++)
        bfr[ks][j] = *(const short8*)(BsT + brow0 + j * 1024 + cs);
    }
    lwait0();
    if (k0 < 192) TSTAGEF(Wf2T, BsT, k0 + 64);
#pragma unroll
    for (int ks = 0; ks < 2; ks++)
#pragma unroll
      for (int i = 0; i < 2; i++)
#pragma unroll
        for (int j = 0; j < 4; j++)
          acc3f[i][j] = __builtin_amdgcn_mfma_f32_16x16x32_bf16(af[ks][i], bfr[ks][j], acc3f[i][j], 0, 0, 0);
  }

  // ---- phase 6: + bf2 + gln residual (f32), write out (nontemporal) ----
#pragma unroll
  for (int j = 0; j < 4; j++) {
    const int colg = wn * 64 + j * 16 + l15;
    const float bj = bf2[colg];
#pragma unroll
    for (int i = 0; i < 2; i++)
#pragma unroll
      for (int r = 0; r < 4; r++) {
        const int row = i * 16 + quad * 4 + r;
        __builtin_nontemporal_store(acc3f[i][j][r] + bj + glnreg[i][j][r],
                                    &out[(rowbase + row) * 256 + colg]);
      }
  }
#undef TSTAGE1
#undef TMM1
#undef TSTAGEF
}

extern "C" void kernel_launch(void* const* d_in, const int* in_sizes, int n_in,
                              void* d_out, int out_size, void* d_ws, size_t ws_size,
                              hipStream_t stream) {
  const float* gnodes = (const float*)d_in[0];
  const int*   graph  = (const int*)d_in[1];
  const float* Wg1 = (const float*)d_in[2];
  const float* bg1 = (const float*)d_in[3];
  const float* Wg2 = (const float*)d_in[4];
  const float* bg2 = (const float*)d_in[5];
  const float* Wf1 = (const float*)d_in[6];
  const float* bf1 = (const float*)d_in[7];
  const float* Wf2 = (const float*)d_in[8];
  const float* bf2 = (const float*)d_in[9];
  const float* ln_a = (const float*)d_in[10];
  const float* ln_b = (const float*)d_in[11];

  float* adj_out = (float*)d_out;
  float* out     = (float*)d_out + 83886080;   // (16,5,1024,1024) f32 first

  char* ws = (char*)d_ws;
  ushort_t* adjb  = (ushort_t*)(ws);                       //  67108864 B (16,2,1024,1024)
  ushort_t* XT    = (ushort_t*)(ws + 67108864);            //   8388608 B (16,256,1024)
  ushort_t* W1T   = (ushort_t*)(ws + 75497472);            //    524288 B
  ushort_t* W2pT  = (ushort_t*)(ws + 76021760);            //    262144 B (2,128,512)
  ushort_t* Wf1T  = (ushort_t*)(ws + 76283904);            //    131072 B
  ushort_t* Wf2T  = (ushort_t*)(ws + 76414976);            //    131072 B
  ushort_t* sup2T = (ushort_t*)(ws + 76546048);            //   8388608 B (16,2,128,1024)

  k_prep<<<84992, 256, 0, stream>>>(graph, adj_out, adjb, gnodes, XT,
                                    Wg1, Wg2, Wf1, Wf2, W1T, W2pT, Wf1T, Wf2T);

  k_mid<<<512, 256, 0, stream>>>(adjb, XT, W1T, bg1, W2pT, sup2T);

  k_tail<<<512, 256, 0, stream>>>(adjb, sup2T, bg2, gnodes, ln_a, ln_b,
                                  Wf1T, bf1, Wf2T, bf2, out);
}